// Round 2
// baseline (407.544 us; speedup 1.0000x reference)
//
#include <hip/hip_runtime.h>
#include <hip/hip_bf16.h>
#include <math.h>

// Problem: B=16, N=1024, D=1024, H=8, HD=128
#define BN 1024
#define DD 1024
#define NB 16
#define NH 8
#define HDIM 128

typedef __attribute__((ext_vector_type(8))) short bf16x8;
typedef __attribute__((ext_vector_type(4))) float f32x4;
typedef __attribute__((ext_vector_type(4))) unsigned short ushort4v;

#define DEV __device__ __forceinline__

DEV unsigned short f2bf(float f) {
  unsigned u = __float_as_uint(f);
  u = (u + 0x7fffu + ((u >> 16) & 1u)) >> 16;  // RNE
  return (unsigned short)u;
}

DEV f32x4 mfma16(bf16x8 a, bf16x8 b, f32x4 c) {
  return __builtin_amdgcn_mfma_f32_16x16x32_bf16(a, b, c, 0, 0, 0);
}

// async global->LDS, 16B per lane. LDS dest = wave-uniform base + lane*16.
DEV void async16(const unsigned short* g, unsigned short* l) {
  __builtin_amdgcn_global_load_lds(
      (const __attribute__((address_space(1))) unsigned short*)g,
      (__attribute__((address_space(3))) unsigned short*)l, 16, 0, 0);
}

// ---------------------------------------------------------------------------
// K0 (fused prep): conv_x | transpose_qkv | transpose_fc, branched on blockIdx
// ---------------------------------------------------------------------------
__global__ __launch_bounds__(256) void prep_kernel(
    const float* __restrict__ x, const float* __restrict__ Wq,
    const float* __restrict__ Wk, const float* __restrict__ Wv,
    const float* __restrict__ Wfc, unsigned short* __restrict__ x_bf,
    unsigned short* __restrict__ wqkvT, unsigned short* __restrict__ wfcT) {
  __shared__ float tile[32][33];
  const int bx = blockIdx.x, tid = threadIdx.x;
  if (bx < 16384) {
    int i = bx * 256 + tid;
    const float4* p = (const float4*)x;
    float4 v = p[i];
    ushort4v o;
    o[0] = f2bf(v.x); o[1] = f2bf(v.y); o[2] = f2bf(v.z); o[3] = f2bf(v.w);
    *(ushort4v*)(x_bf + (size_t)i * 4) = o;
    return;
  }
  const int tx = tid & 31, ty = tid >> 5;
  if (bx < 19456) {
    int idx = bx - 16384;
    int k0 = (idx & 31) * 32, e0 = ((idx >> 5) & 3) * 32, z = idx >> 7;
    int which = z >> 3, h = z & 7;
    const float* in = (which == 0 ? Wq : (which == 1 ? Wk : Wv)) + (size_t)h * DD * HDIM;
#pragma unroll
    for (int i = 0; i < 4; ++i)
      tile[ty + i * 8][tx] = in[(size_t)(k0 + ty + i * 8) * HDIM + e0 + tx];
    __syncthreads();
    int rowbase = which * 1024 + h * 128 + e0;
#pragma unroll
    for (int i = 0; i < 4; ++i)
      wqkvT[(size_t)(rowbase + ty + i * 8) * DD + k0 + tx] = f2bf(tile[tx][ty + i * 8]);
  } else {
    int idx = bx - 19456;
    int d0 = (idx & 31) * 32, c0 = (idx >> 5) * 32;
#pragma unroll
    for (int i = 0; i < 4; ++i)
      tile[ty + i * 8][tx] = Wfc[(size_t)(d0 + ty + i * 8) * DD + c0 + tx];
    __syncthreads();
#pragma unroll
    for (int i = 0; i < 4; ++i)
      wfcT[(size_t)(c0 + ty + i * 8) * DD + d0 + tx] = f2bf(tile[tx][ty + i * 8]);
  }
}

// ---------------------------------------------------------------------------
// GEMM v3: 256x256 tile, BK=64, 512 threads (8 waves 2Mx4N interleaved),
// 4 phases/K-tile with DEEP counted-vmcnt schedule (m201 re-timing).
//
// R1 post-mortem: v2 waited 3x per K-tile forcing loads issued only 2-3
// phases (~300-460cy) earlier -> latency stall at every wait -> MfmaUtil 33%.
// v3: stage mapping shifted a full K-tile deeper; ONE wait per K-tile.
//
// Per K-tile T (buf = T&1), phases:
//  Ph1: ds A-lo(T)+B-lo(T) frags            ; MFMA acc[0..3][0..1]
//  Ph2: ds B-hi(T); stage A-lo(T+2)         ; MFMA acc[0..3][2..3]
//  Ph3: ds A-hi(T); stage B-lo(T+2)         ; MFMA acc[4..7][2..3]
//  Ph4: stage B-hi(T+2)+A-hi(T+2); vmcnt(8) ; MFMA acc[4..7][0..1]
// Each stage targets a region whose last read was >=1 barrier earlier.
// FIFO invariant: Ph4(T)'s vmcnt(8) forces exactly tile T+1's 8 loads
// (issued 4-6 phases = 600-900cy earlier); tile T+2's 8 stay in flight.
// Prologue: stage tiles 0,1 fully (16 loads), vmcnt(8) forces tile 0.
//
// LDS: [2][256][64] bf16 per operand = 128 KB, row-rotation swizzle
// LDS[r][c] = G[r][(c-r)&7] (pre-swizzled global src, linear gl_lds dest;
// read chunk rotation (quad+row)&7) -- measured 0 bank conflicts.
// 1 block/CU (LDS-bound), 2 waves/SIMD.
// ---------------------------------------------------------------------------
template <int MODE>
__global__ __launch_bounds__(512, 2) void gemm256_kernel(
    const unsigned short* __restrict__ A, const unsigned short* __restrict__ Bt,
    const float* __restrict__ bias0, const float* __restrict__ bias1,
    const float* __restrict__ bias2, unsigned short* __restrict__ out0,
    unsigned short* __restrict__ out1, unsigned short* __restrict__ out2,
    float* __restrict__ outf) {
  __shared__ unsigned short As[2][256 * 64];
  __shared__ unsigned short Bs[2][256 * 64];
  const int tid = threadIdx.x;
  const int w = tid >> 6, lane = tid & 63, quad = lane >> 4, l15 = lane & 15;
  const int wr = w >> 2, wc = w & 3;

  // XCD-aware bijective swizzle (nwg % 8 == 0 for both modes)
  constexpr int NBN = (MODE == 0) ? 12 : 4;   // n-blocks
  constexpr int CPX = (MODE == 0) ? 96 : 32;  // blocks per XCD
  const int bid = blockIdx.x;
  const int swz = (bid & 7) * CPX + (bid >> 3);
  const int mblk = swz / NBN, nblk = swz - mblk * NBN;
  const int m0 = mblk << 8, n0 = nblk << 8;

  // staging addresses: thread t covers row (t>>3) of each 64-row group,
  // global chunk ((t&7) - row) & 7  (rotation pre-swizzle)
  const int srow = tid >> 3;
  const int gch = ((tid & 7) - srow) & 7;
  const unsigned short* ag = A + (size_t)(m0 + srow) * 1024 + gch * 8;
  const unsigned short* bg = Bt + (size_t)(n0 + srow) * 1024 + gch * 8;
  const int wbase = w * 512;  // elems: wave-uniform LDS base within 64-row group

  // fragment read column rotation: chunk = (ks*4 + quad + row)&7, row%8 == l15%8
  const int sl0 = ((quad + l15) & 7) * 8;
  const int sl1 = ((quad + l15 + 4) & 7) * 8;

  f32x4 acc[8][4] = {};
  bf16x8 af[4][2];   // A frags of current m-half (overwritten Ph1 -> Ph3)
  bf16x8 bfr[4][2];  // B frags: [0..1]=n-lo (Ph1), [2..3]=n-hi (Ph2)

  // staging helpers (half-tile = 2 x async16 of 64 rows each)
#define STAGE_A_LO(buf, kb) do { \
    async16(ag + (kb), &As[buf][0] + wbase); \
    async16(ag + (kb) + 64 * 1024, &As[buf][64 * 64] + wbase); } while (0)
#define STAGE_A_HI(buf, kb) do { \
    async16(ag + (kb) + 128 * 1024, &As[buf][128 * 64] + wbase); \
    async16(ag + (kb) + 192 * 1024, &As[buf][192 * 64] + wbase); } while (0)
#define STAGE_B_LO(buf, kb) do { \
    async16(bg + (kb), &Bs[buf][0] + wbase); \
    async16(bg + (kb) + 64 * 1024, &Bs[buf][64 * 64] + wbase); } while (0)
#define STAGE_B_HI(buf, kb) do { \
    async16(bg + (kb) + 128 * 1024, &Bs[buf][128 * 64] + wbase); \
    async16(bg + (kb) + 192 * 1024, &Bs[buf][192 * 64] + wbase); } while (0)

  // ---- prologue: stage tiles 0 and 1 fully; force tile 0 complete ----
  STAGE_A_LO(0, 0); STAGE_B_LO(0, 0); STAGE_B_HI(0, 0); STAGE_A_HI(0, 0);
  STAGE_A_LO(1, 64); STAGE_B_LO(1, 64); STAGE_B_HI(1, 64); STAGE_A_HI(1, 64);
  asm volatile("s_waitcnt vmcnt(8)" ::: "memory");
  __builtin_amdgcn_s_barrier();

  for (int t = 0; t < 16; ++t) {
    const int cur = t & 1;
    const unsigned short* ac = &As[cur][0];
    const unsigned short* bc = &Bs[cur][0];
    const int kb2 = ((t + 2) & 15) * 64;  // tile T+2 (wraps: harmless re-read)

    // ---- Ph1: ds A-lo + B-lo; no stage; MFMA m-lo x n-lo
#pragma unroll
    for (int mt = 0; mt < 4; ++mt) {
      const unsigned short* rp = ac + (wr * 16 + mt * 32 + l15) * 64;
      af[mt][0] = *(const bf16x8*)(rp + sl0);
      af[mt][1] = *(const bf16x8*)(rp + sl1);
    }
#pragma unroll
    for (int nt = 0; nt < 2; ++nt) {
      const unsigned short* rp = bc + (wc * 16 + nt * 64 + l15) * 64;
      bfr[nt][0] = *(const bf16x8*)(rp + sl0);
      bfr[nt][1] = *(const bf16x8*)(rp + sl1);
    }
    __builtin_amdgcn_s_barrier();
    asm volatile("s_waitcnt lgkmcnt(0)" ::: "memory");
    __builtin_amdgcn_s_setprio(1);
#pragma unroll
    for (int mt = 0; mt < 4; ++mt)
#pragma unroll
      for (int nt = 0; nt < 2; ++nt) {
        acc[mt][nt] = mfma16(af[mt][0], bfr[nt][0], acc[mt][nt]);
        acc[mt][nt] = mfma16(af[mt][1], bfr[nt][1], acc[mt][nt]);
      }
    __builtin_amdgcn_s_setprio(0);
    __builtin_amdgcn_s_barrier();

    // ---- Ph2: ds B-hi; stage A-lo(T+2) [region freed after Ph1]
#pragma unroll
    for (int nt = 0; nt < 2; ++nt) {
      const unsigned short* rp = bc + (wc * 16 + 128 + nt * 64 + l15) * 64;
      bfr[2 + nt][0] = *(const bf16x8*)(rp + sl0);
      bfr[2 + nt][1] = *(const bf16x8*)(rp + sl1);
    }
    STAGE_A_LO(cur, kb2);
    __builtin_amdgcn_s_barrier();
    asm volatile("s_waitcnt lgkmcnt(0)" ::: "memory");
    __builtin_amdgcn_s_setprio(1);
#pragma unroll
    for (int mt = 0; mt < 4; ++mt)
#pragma unroll
      for (int nt = 0; nt < 2; ++nt) {
        acc[mt][2 + nt] = mfma16(af[mt][0], bfr[2 + nt][0], acc[mt][2 + nt]);
        acc[mt][2 + nt] = mfma16(af[mt][1], bfr[2 + nt][1], acc[mt][2 + nt]);
      }
    __builtin_amdgcn_s_setprio(0);
    __builtin_amdgcn_s_barrier();

    // ---- Ph3: ds A-hi (overwrite af); stage B-lo(T+2) [freed after Ph1]
#pragma unroll
    for (int mt = 0; mt < 4; ++mt) {
      const unsigned short* rp = ac + (wr * 16 + 128 + mt * 32 + l15) * 64;
      af[mt][0] = *(const bf16x8*)(rp + sl0);
      af[mt][1] = *(const bf16x8*)(rp + sl1);
    }
    STAGE_B_LO(cur, kb2);
    __builtin_amdgcn_s_barrier();
    asm volatile("s_waitcnt lgkmcnt(0)" ::: "memory");
    __builtin_amdgcn_s_setprio(1);
#pragma unroll
    for (int mt = 0; mt < 4; ++mt)
#pragma unroll
      for (int nt = 0; nt < 2; ++nt) {
        acc[4 + mt][2 + nt] = mfma16(af[mt][0], bfr[2 + nt][0], acc[4 + mt][2 + nt]);
        acc[4 + mt][2 + nt] = mfma16(af[mt][1], bfr[2 + nt][1], acc[4 + mt][2 + nt]);
      }
    __builtin_amdgcn_s_setprio(0);
    __builtin_amdgcn_s_barrier();

    // ---- Ph4: stage B-hi(T+2) [freed Ph2] + A-hi(T+2) [freed Ph3];
    //           ONE wait: vmcnt(8) forces exactly tile T+1's 8 loads.
    STAGE_B_HI(cur, kb2);
    STAGE_A_HI(cur, kb2);
    asm volatile("s_waitcnt vmcnt(8)" ::: "memory");
    __builtin_amdgcn_s_barrier();
    __builtin_amdgcn_s_setprio(1);
#pragma unroll
    for (int mt = 0; mt < 4; ++mt)
#pragma unroll
      for (int nt = 0; nt < 2; ++nt) {
        acc[4 + mt][nt] = mfma16(af[mt][0], bfr[nt][0], acc[4 + mt][nt]);
        acc[4 + mt][nt] = mfma16(af[mt][1], bfr[nt][1], acc[4 + mt][nt]);
      }
    __builtin_amdgcn_s_setprio(0);
    __builtin_amdgcn_s_barrier();
  }
#undef STAGE_A_LO
#undef STAGE_A_HI
#undef STAGE_B_LO
#undef STAGE_B_HI

  // ---- epilogue ----
  if constexpr (MODE == 0) {
    const int seg = n0 >> 10;  // 0=q 1=k 2=v (256-tile never straddles segs)
    const float* bp = (seg == 0) ? bias0 : (seg == 1 ? bias1 : bias2);
#pragma unroll
    for (int ai = 0; ai < 8; ++ai) {
      int mb = m0 + wr * 16 + ai * 32 + quad * 4;
      int bb = mb >> 10, nn = mb & 1023;
#pragma unroll
      for (int nt = 0; nt < 4; ++nt) {
        int c = n0 + wc * 16 + nt * 64 + l15;
        int cc = c & 1023;
        int h = cc >> 7, e = cc & 127;
        float bias = bp[cc];
        if (seg == 2) {
          ushort4v pv;
#pragma unroll
          for (int r = 0; r < 4; ++r) pv[r] = f2bf(acc[ai][nt][r] + bias);
          *(ushort4v*)(out2 + ((size_t)(bb * NH + h) * HDIM + e) * BN + nn) = pv;
        } else {
          unsigned short* op = (seg == 0) ? out0 : out1;
#pragma unroll
          for (int r = 0; r < 4; ++r)
            op[(((size_t)bb * NH + h) * BN + (nn + r)) * HDIM + e] =
                f2bf(acc[ai][nt][r] + bias);
        }
      }
    }
  } else {
#pragma unroll
    for (int ai = 0; ai < 8; ++ai) {
      int mb = m0 + wr * 16 + ai * 32 + quad * 4;
#pragma unroll
      for (int nt = 0; nt < 4; ++nt) {
        int c = n0 + wc * 16 + nt * 64 + l15;
        float bias = bias0[c];
#pragma unroll
        for (int r = 0; r < 4; ++r)
          outf[(size_t)(mb + r) * DD + c] = acc[ai][nt][r] + bias;
      }
    }
  }
}

// ---------------------------------------------------------------------------
// K4: flash attention v6 — 2x2 wave split to kill LDS-read redundancy.
// (unchanged this round)
// ---------------------------------------------------------------------------
__global__ __launch_bounds__(256, 2) void flash_attn_kernel(
    const unsigned short* __restrict__ Q, const unsigned short* __restrict__ Kk,
    const unsigned short* __restrict__ Vt, const int* __restrict__ xmask,
    unsigned short* __restrict__ O) {
  __shared__ unsigned short k_s[64 * 128];       // 16 KB, swizzled
  __shared__ unsigned short v_s[2][128 * 64];    // 32 KB, swizzled, dbuf
  __shared__ unsigned short p_s[128 * 72];       // 18 KB, padded (shared P)
  __shared__ float l_s[2][128];                  // 1 KB

  const float CL2E = 0.08838834764831845f * 1.44269504088896f;  // SCALE*log2(e)

  const int tid = threadIdx.x;
  const int w = tid >> 6, lane = tid & 63, quad = lane >> 4, l15 = lane & 15;
  const int wq = w >> 1, wk = w & 1;             // we == wk
  const int lin = blockIdx.x;
  const int bh = lin & 127, qb = lin >> 7;
  const int b = bh >> 3, h = bh & 7;
  const int q0 = qb * 128;
  const unsigned short* qp = Q + ((size_t)bh * BN + q0) * HDIM;
  const unsigned short* kp = Kk + (size_t)bh * BN * HDIM;
  const unsigned short* vp = Vt + (size_t)bh * HDIM * BN;
  const int* xm_b = xmask + b * BN;

  // Q fragments (A-layout) for 64 rows: row = wq*64 + mt*16 + l15
  bf16x8 qf[4][4];
#pragma unroll
  for (int mt = 0; mt < 4; ++mt)
#pragma unroll
    for (int ks = 0; ks < 4; ++ks)
      qf[mt][ks] = *(const bf16x8*)(qp + (wq * 64 + mt * 16 + l15) * HDIM + ks * 32 + quad * 8);

  // row masks packed: bit (mt*4+r) for row wq*64 + mt*16 + quad*4 + r
  int rowm_bits = 0;
#pragma unroll
  for (int mt = 0; mt < 4; ++mt)
#pragma unroll
    for (int r = 0; r < 4; ++r)
      rowm_bits |= (xm_b[q0 + wq * 64 + mt * 16 + quad * 4 + r] ? 1 : 0) << (mt * 4 + r);

  // staging lane decomposition (same swizzles as R5: measured conflict-free)
  const int krow = lane >> 4;
  const int vrow = lane >> 3;
  const int vch = ((lane & 7) - vrow) & 7;

  float l_lane[4][4] = {};
  f32x4 o_acc[4][4] = {};

  // pre-issue tile 0
#pragma unroll
  for (int i = 0; i < 4; ++i) {
    int rmod = i * 4 + krow;
    int g = ((lane & 15) - rmod) & 15;
    async16(kp + (size_t)(w * 16 + rmod) * HDIM + g * 8, k_s + (w * 16 + i * 4) * 128);
    int e = w * 32 + i * 8 + vrow;
    async16(vp + (size_t)e * BN + vch * 8, v_s[0] + (w * 32 + i * 8) * 64);
  }

  for (int it = 0; it < 16; ++it) {
    const int kb = it * 64;
    int cm0 = xm_b[kb + wk * 32 + l15];
    int cm1 = xm_b[kb + wk * 32 + 16 + l15];
    __syncthreads();  // sync_a: K/V tiles arrived; prev p_s reads done

    // S slice = Q[wq-half] K^T[wk-half]  (64q x 32k)
    f32x4 s[4][2] = {};
#pragma unroll
    for (int ks = 0; ks < 4; ++ks) {
      const int sl = ((ks * 4 + quad + l15) & 15) * 8;
      bf16x8 b0 = *(const bf16x8*)(k_s + (wk * 32 + l15) * 128 + sl);
      bf16x8 b1 = *(const bf16x8*)(k_s + (wk * 32 + 16 + l15) * 128 + sl);
#pragma unroll
      for (int mt = 0; mt < 4; ++mt) {
        s[mt][0] = mfma16(qf[mt][ks], b0, s[mt][0]);
        s[mt][1] = mfma16(qf[mt][ks], b1, s[mt][1]);
      }
    }

    // fixed-max softmax -> shared p_s, accumulate partial l per lane
#pragma unroll
    for (int mt = 0; mt < 4; ++mt)
#pragma unroll
      for (int nt = 0; nt < 2; ++nt) {
        int cmv = nt ? cm1 : cm0;
#pragma unroll
        for (int r = 0; r < 4; ++r) {
          float xs = s[mt][nt][r] * CL2E;
          float t = cmv ? xs : -60.0f;
          int rb = (rowm_bits >> (mt * 4 + r)) & 1;
          float e2 = rb ? t : 0.0f;
          float p = __builtin_amdgcn_exp2f(e2);
          l_lane[mt][r] += p;
          p_s[(wq * 64 + mt * 16 + quad * 4 + r) * 72 + wk * 32 + nt * 16 + l15] = f2bf(p);
        }
      }

    __syncthreads();  // sync_b: p_s complete; all k_s reads done

    // prefetch next K/V (wrapped on last iter; harmless re-read)
    {
      const int kn = (kb + 64) & (BN - 1);
      unsigned short* vb_next = v_s[(it + 1) & 1];
#pragma unroll
      for (int i = 0; i < 4; ++i) {
        int rmod = i * 4 + krow;
        int g = ((lane & 15) - rmod) & 15;
        async16(kp + (size_t)(kn + w * 16 + rmod) * HDIM + g * 8,
                k_s + (w * 16 + i * 4) * 128);
        int e = w * 32 + i * 8 + vrow;
        async16(vp + (size_t)e * BN + kn + vch * 8, vb_next + (w * 32 + i * 8) * 64);
      }
    }

    // O slice += P[wq-half][64k] V[64k][we-half]  (64q x 64e)
    const unsigned short* vb = v_s[it & 1];
#pragma unroll
    for (int ks2 = 0; ks2 < 2; ++ks2) {
      const int sl = ((ks2 * 4 + quad + l15) & 7) * 8;
      bf16x8 pa[4];
#pragma unroll
      for (int mt = 0; mt < 4; ++mt)
        pa[mt] = *(const bf16x8*)(p_s + (wq * 64 + mt * 16 + l15) * 72 + ks2 * 32 + quad * 8);
#pragma unroll
      for (int et = 0; et < 4; ++et) {
        bf16x8 bv = *(const bf16x8*)(vb + (wk * 64 + et * 16 + l15) * 64 + sl);
#pragma unroll
        for (int mt = 0; mt < 4; ++mt)
          o_acc[mt][et] = mfma16(pa[mt], bv, o_acc[mt][et]);
      }
    }
  }

  // merge partial l across the two k-half waves via LDS
#pragma unroll
  for (int mt = 0; mt < 4; ++mt)
#pragma unroll
    for (int r = 0; r < 4; ++r) {
      float l = l_lane[mt][r];
#pragma unroll
      for (int off = 1; off < 16; off <<= 1) l += __shfl_xor(l, off, 64);
      if (l15 == 0) l_s[wk][wq * 64 + mt * 16 + quad * 4 + r] = l;
    }
  __syncthreads();

  // epilogue: O/l, store slice [64q x 64e]
#pragma unroll
  for (int mt = 0; mt < 4; ++mt)
#pragma unroll
    for (int r = 0; r < 4; ++r) {
      int rl = wq * 64 + mt * 16 + quad * 4 + r;
      float inv = 1.0f / (l_s[0][rl] + l_s[1][rl]);
      int row = q0 + rl;
#pragma unroll
      for (int et = 0; et < 4; ++et) {
        int col = h * HDIM + wk * 64 + et * 16 + l15;
        O[((size_t)b * BN + row) * DD + col] = f2bf(o_acc[mt][et][r] * inv);
      }
    }
}

// ---------------------------------------------------------------------------
// Workspace layout (bytes): total ~168 MB
//   x_bf @0 33554432 | wqkvT @33554432 6291456 | wfcT @39845888 2097152
//   q_bf @41943040 | k_bf @75497472 | vT_bf @109051904 | o_bf @142606336 (each 33554432)
// ---------------------------------------------------------------------------
extern "C" void kernel_launch(void* const* d_in, const int* in_sizes, int n_in,
                              void* d_out, int out_size, void* d_ws, size_t ws_size,
                              hipStream_t stream) {
  const float* x = (const float*)d_in[0];
  const int* xmask = (const int*)d_in[1];
  const float* Wq = (const float*)d_in[2];
  const float* bq = (const float*)d_in[3];
  const float* Wk = (const float*)d_in[4];
  const float* bk = (const float*)d_in[5];
  const float* Wv = (const float*)d_in[6];
  const float* bv = (const float*)d_in[7];
  const float* Wfc = (const float*)d_in[8];
  const float* bfc = (const float*)d_in[9];
  float* out = (float*)d_out;

  char* ws = (char*)d_ws;
  unsigned short* x_bf  = (unsigned short*)(ws);
  unsigned short* wqkvT = (unsigned short*)(ws + 33554432);
  unsigned short* wfcT  = (unsigned short*)(ws + 39845888);
  unsigned short* q_bf  = (unsigned short*)(ws + 41943040);
  unsigned short* k_bf  = (unsigned short*)(ws + 75497472);
  unsigned short* vT_bf = (unsigned short*)(ws + 109051904);
  unsigned short* o_bf  = (unsigned short*)(ws + 142606336);

  prep_kernel<<<dim3(20480), dim3(256), 0, stream>>>(x, Wq, Wk, Wv, Wfc, x_bf, wqkvT, wfcT);

  // QKV: M=16384, N=3072 -> 64 x 12 = 768 blocks (exactly 3 waves of 256 CUs)
  gemm256_kernel<0><<<dim3(768), dim3(512), 0, stream>>>(
      x_bf, wqkvT, bq, bk, bv, q_bf, k_bf, vT_bf, nullptr);

  flash_attn_kernel<<<dim3(1024), dim3(256), 0, stream>>>(q_bf, k_bf, vT_bf, xmask, o_bf);

  // FC: M=16384, N=1024 -> 64 x 4 = 256 blocks (exactly 1 per CU)
  gemm256_kernel<1><<<dim3(256), dim3(512), 0, stream>>>(
      o_bf, wfcT, bfc, nullptr, nullptr, nullptr, nullptr, nullptr, out);
}

// Round 3
// 400.871 us; speedup vs baseline: 1.0166x; 1.0166x over previous
//
#include <hip/hip_runtime.h>
#include <hip/hip_bf16.h>
#include <math.h>

// Problem: B=16, N=1024, D=1024, H=8, HD=128
#define BN 1024
#define DD 1024
#define NB 16
#define NH 8
#define HDIM 128

typedef __attribute__((ext_vector_type(8))) short bf16x8;
typedef __attribute__((ext_vector_type(4))) float f32x4;
typedef __attribute__((ext_vector_type(4))) unsigned short ushort4v;

#define DEV __device__ __forceinline__

DEV unsigned short f2bf(float f) {
  unsigned u = __float_as_uint(f);
  u = (u + 0x7fffu + ((u >> 16) & 1u)) >> 16;  // RNE
  return (unsigned short)u;
}

DEV f32x4 mfma16(bf16x8 a, bf16x8 b, f32x4 c) {
  return __builtin_amdgcn_mfma_f32_16x16x32_bf16(a, b, c, 0, 0, 0);
}

// async global->LDS, 16B per lane. LDS dest = wave-uniform base + lane*16.
DEV void async16(const unsigned short* g, unsigned short* l) {
  __builtin_amdgcn_global_load_lds(
      (const __attribute__((address_space(1))) unsigned short*)g,
      (__attribute__((address_space(3))) unsigned short*)l, 16, 0, 0);
}

// ---------------------------------------------------------------------------
// K0 (fused prep): conv_x | transpose_qkv | transpose_fc, branched on blockIdx
// ---------------------------------------------------------------------------
__global__ __launch_bounds__(256) void prep_kernel(
    const float* __restrict__ x, const float* __restrict__ Wq,
    const float* __restrict__ Wk, const float* __restrict__ Wv,
    const float* __restrict__ Wfc, unsigned short* __restrict__ x_bf,
    unsigned short* __restrict__ wqkvT, unsigned short* __restrict__ wfcT) {
  __shared__ float tile[32][33];
  const int bx = blockIdx.x, tid = threadIdx.x;
  if (bx < 16384) {
    int i = bx * 256 + tid;
    const float4* p = (const float4*)x;
    float4 v = p[i];
    ushort4v o;
    o[0] = f2bf(v.x); o[1] = f2bf(v.y); o[2] = f2bf(v.z); o[3] = f2bf(v.w);
    *(ushort4v*)(x_bf + (size_t)i * 4) = o;
    return;
  }
  const int tx = tid & 31, ty = tid >> 5;
  if (bx < 19456) {
    int idx = bx - 16384;
    int k0 = (idx & 31) * 32, e0 = ((idx >> 5) & 3) * 32, z = idx >> 7;
    int which = z >> 3, h = z & 7;
    const float* in = (which == 0 ? Wq : (which == 1 ? Wk : Wv)) + (size_t)h * DD * HDIM;
#pragma unroll
    for (int i = 0; i < 4; ++i)
      tile[ty + i * 8][tx] = in[(size_t)(k0 + ty + i * 8) * HDIM + e0 + tx];
    __syncthreads();
    int rowbase = which * 1024 + h * 128 + e0;
#pragma unroll
    for (int i = 0; i < 4; ++i)
      wqkvT[(size_t)(rowbase + ty + i * 8) * DD + k0 + tx] = f2bf(tile[tx][ty + i * 8]);
  } else {
    int idx = bx - 19456;
    int d0 = (idx & 31) * 32, c0 = (idx >> 5) * 32;
#pragma unroll
    for (int i = 0; i < 4; ++i)
      tile[ty + i * 8][tx] = Wfc[(size_t)(d0 + ty + i * 8) * DD + c0 + tx];
    __syncthreads();
#pragma unroll
    for (int i = 0; i < 4; ++i)
      wfcT[(size_t)(c0 + ty + i * 8) * DD + d0 + tx] = f2bf(tile[tx][ty + i * 8]);
  }
}

// ---------------------------------------------------------------------------
// GEMM v4: 256x256 tile, BK=64, 8 waves (2Mx4N), LDS-read SOFTWARE PIPELINE.
//
// R2 post-mortem: v2/v3's barrier+lgkmcnt(0)-before-MFMA serialized the
// CU-wide LDS burst (up to 96KB ~1150cy) against the MFMA cluster (621cy)
// every phase -> 5600-6300cy/K-tile vs 2100 MFMA floor -> MfmaUtil 32%.
//
// v4: fragment reads issued ONE CLUSTER AHEAD; NO lgkmcnt(0) in loop --
// the compiler emits fine-grained lgkmcnt(4/8) from register deps, so LDS
// service overlaps the previous cluster's MFMA.
//
// Clusters per K-tile T (per wave, acc rows ai=0..7 = m-frags, nt=0..3):
//  C1 = m-lo x all-n x kk0   C2 = m-lo x all-n x kk1
//  C3 = m-hi x all-n x kk0   C4 = m-hi x all-n x kk1   (16 indep MFMA each)
// Reads (b128/wave): R1={A-lo-k0,B-k0}:8  R2={A-lo-k1,B-k1}:8
//                    R3={A-hi-k0}:4       R4={A-hi-k1}:4
//
// Iteration t (c=t&1, o=c^1; buffers: buf c holds tile t, buf o tile t+1):
//  P1: reads R2(t) from c; stage A-hi(t+1)->o;           MFMA C1
//  P2: vmcnt(8); BARRIER; schedbar; reads R3(t) from c;  MFMA C2; BARRIER
//  P3: stage A-lo,B-lo(t+2)->c; reads R4(t) from c;      MFMA C3
//  P4: stage B-hi(t+2)->c; vmcnt(8); BARRIER; schedbar;
//      reads R1(t+1) from o;                             MFMA C4; BARRIER
//
// Formal safety (all proven by queue simulation):
//  - region recycle: every stage is preceded by a barrier that follows the
//    lgkm-completion (via consuming cluster's wait) of all reads of the old
//    contents (A-hi: P4-end bar; A-lo/B-lo/B-hi: P2-end bar).
//  - fresh reads: R3 after vmcnt(8)@P2+bar forces A-hi(t) (staged P1(t-1));
//    R1(t+1) after vmcnt(8)@P4+bar forces A-lo/B-lo/B-hi(t+1) (staged
//    P3/P4(t-1)). Steady-state queue: 10->8 @P2, 14->8 @P4; never drained.
//  - prologue establishes the invariant: 14 issued, vmcnt(8) forces tile-0
//    A-lo/B-lo/B-hi, then R1(0) pre-read.
//
// LDS: [2][256][64] bf16 per operand = 128 KB, row-rotation swizzle
// (pre-swizzled global src, linear gl_lds dest; read chunk (kchunk+row)&7)
// -- measured 0 bank conflicts. 1 block/CU, 2 waves/SIMD.
// ---------------------------------------------------------------------------
template <int MODE>
__global__ __launch_bounds__(512, 2) void gemm256_kernel(
    const unsigned short* __restrict__ A, const unsigned short* __restrict__ Bt,
    const float* __restrict__ bias0, const float* __restrict__ bias1,
    const float* __restrict__ bias2, unsigned short* __restrict__ out0,
    unsigned short* __restrict__ out1, unsigned short* __restrict__ out2,
    float* __restrict__ outf) {
  __shared__ unsigned short As[2][256 * 64];
  __shared__ unsigned short Bs[2][256 * 64];
  const int tid = threadIdx.x;
  const int w = tid >> 6, lane = tid & 63, quad = lane >> 4, l15 = lane & 15;
  const int wr = w >> 2, wc = w & 3;

  // XCD-aware bijective swizzle (nwg % 8 == 0 for both modes)
  constexpr int NBN = (MODE == 0) ? 12 : 4;   // n-blocks
  constexpr int CPX = (MODE == 0) ? 96 : 32;  // blocks per XCD
  const int bid = blockIdx.x;
  const int swz = (bid & 7) * CPX + (bid >> 3);
  const int mblk = swz / NBN, nblk = swz - mblk * NBN;
  const int m0 = mblk << 8, n0 = nblk << 8;

  // staging addresses: thread t covers row (t>>3) of each 64-row group,
  // global chunk ((t&7) - row) & 7  (rotation pre-swizzle)
  const int srow = tid >> 3;
  const int gch = ((tid & 7) - srow) & 7;
  const unsigned short* ag = A + (size_t)(m0 + srow) * 1024 + gch * 8;
  const unsigned short* bg = Bt + (size_t)(n0 + srow) * 1024 + gch * 8;
  const int wbase = w * 512;  // elems: wave-uniform LDS base within 64-row group

  // fragment read column rotation: chunk = (kchunk + row)&7, row%8 == l15%8
  const int sl0 = ((quad + l15) & 7) * 8;       // kk0: chunks 0..3
  const int sl1 = ((quad + 4 + l15) & 7) * 8;   // kk1: chunks 4..7

  f32x4 acc[8][4] = {};
  bf16x8 aK0[4], aK1[4];  // A frags: kk0 / kk1 of current m-half (ping by phase)
  bf16x8 bK0[4], bK1[4];  // B frags all-n: kk0 / kk1

#define STAGE_A_LO(buf, kb) do { \
    async16(ag + (kb), &As[buf][0] + wbase); \
    async16(ag + (kb) + 64 * 1024, &As[buf][64 * 64] + wbase); } while (0)
#define STAGE_A_HI(buf, kb) do { \
    async16(ag + (kb) + 128 * 1024, &As[buf][128 * 64] + wbase); \
    async16(ag + (kb) + 192 * 1024, &As[buf][192 * 64] + wbase); } while (0)
#define STAGE_B_LO(buf, kb) do { \
    async16(bg + (kb), &Bs[buf][0] + wbase); \
    async16(bg + (kb) + 64 * 1024, &Bs[buf][64 * 64] + wbase); } while (0)
#define STAGE_B_HI(buf, kb) do { \
    async16(bg + (kb) + 128 * 1024, &Bs[buf][128 * 64] + wbase); \
    async16(bg + (kb) + 192 * 1024, &Bs[buf][192 * 64] + wbase); } while (0)
#define READ_A(dst, buf, moff, slx) do { \
    _Pragma("unroll") \
    for (int mt = 0; mt < 4; ++mt) \
      dst[mt] = *(const bf16x8*)(&As[buf][0] + (wr * 16 + (moff) + mt * 32 + l15) * 64 + (slx)); \
    } while (0)
#define READ_B(dst, buf, slx) do { \
    _Pragma("unroll") \
    for (int nt = 0; nt < 4; ++nt) \
      dst[nt] = *(const bf16x8*)(&Bs[buf][0] + (wc * 16 + nt * 64 + l15) * 64 + (slx)); \
    } while (0)
#define CLUSTER(base, a, b) do { \
    __builtin_amdgcn_s_setprio(1); \
    _Pragma("unroll") \
    for (int mt = 0; mt < 4; ++mt) \
      _Pragma("unroll") \
      for (int nt = 0; nt < 4; ++nt) \
        acc[(base) + mt][nt] = mfma16(a[mt], b[nt], acc[(base) + mt][nt]); \
    __builtin_amdgcn_s_setprio(0); } while (0)

  // ---- prologue: queue order [Alo0,Blo0][Bhi0][Ahi0][Alo1,Blo1][Bhi1] = 14
  STAGE_A_LO(0, 0); STAGE_B_LO(0, 0);
  STAGE_B_HI(0, 0);
  STAGE_A_HI(0, 0);
  STAGE_A_LO(1, 64); STAGE_B_LO(1, 64);
  STAGE_B_HI(1, 64);
  asm volatile("s_waitcnt vmcnt(8)" ::: "memory");  // forces Alo0,Blo0,Bhi0
  __builtin_amdgcn_s_barrier();
  __builtin_amdgcn_sched_barrier(0);
  READ_A(aK0, 0, 0, sl0);   // R1(0): A-lo-k0
  READ_B(bK0, 0, sl0);      //        B-k0

  for (int t = 0; t < 16; ++t) {
    const int cur = t & 1, oth = cur ^ 1;
    const int kb1 = ((t + 1) & 15) * 64;
    const int kb2 = ((t + 2) & 15) * 64;

    // ---- P1: reads R2(t); stage A-hi(t+1)->oth; MFMA C1 (waits R1)
    READ_A(aK1, cur, 0, sl1);
    READ_B(bK1, cur, sl1);
    STAGE_A_HI(oth, kb1);
    CLUSTER(0, aK0, bK0);

    // ---- P2: vmcnt(8) [forces A-hi(t)]; barrier; reads R3(t); MFMA C2; barrier
    asm volatile("s_waitcnt vmcnt(8)" ::: "memory");
    __builtin_amdgcn_s_barrier();
    __builtin_amdgcn_sched_barrier(0);
    READ_A(aK0, cur, 128, sl0);
    CLUSTER(0, aK1, bK1);
    __builtin_amdgcn_s_barrier();  // region-recycle: R1/R2 reads complete CU-wide

    // ---- P3: stage A-lo,B-lo(t+2)->cur; reads R4(t); MFMA C3
    STAGE_A_LO(cur, kb2); STAGE_B_LO(cur, kb2);
    READ_A(aK1, cur, 128, sl1);
    CLUSTER(4, aK0, bK0);

    // ---- P4: stage B-hi(t+2)->cur; vmcnt(8) [forces tile t+1 Alo/Blo/Bhi];
    //          barrier; reads R1(t+1) from oth; MFMA C4; barrier
    STAGE_B_HI(cur, kb2);
    asm volatile("s_waitcnt vmcnt(8)" ::: "memory");
    __builtin_amdgcn_s_barrier();
    __builtin_amdgcn_sched_barrier(0);
    READ_A(aK0, oth, 0, sl0);
    READ_B(bK0, oth, sl0);
    CLUSTER(4, aK1, bK1);
    __builtin_amdgcn_s_barrier();  // region-recycle: R3/R4 reads complete CU-wide
  }
  asm volatile("s_waitcnt vmcnt(0)" ::: "memory");  // drain DMA before LDS dealloc

#undef STAGE_A_LO
#undef STAGE_A_HI
#undef STAGE_B_LO
#undef STAGE_B_HI
#undef READ_A
#undef READ_B
#undef CLUSTER

  // ---- epilogue ----
  if constexpr (MODE == 0) {
    const int seg = n0 >> 10;  // 0=q 1=k 2=v (256-tile never straddles segs)
    const float* bp = (seg == 0) ? bias0 : (seg == 1 ? bias1 : bias2);
#pragma unroll
    for (int ai = 0; ai < 8; ++ai) {
      int mb = m0 + wr * 16 + ai * 32 + quad * 4;
      int bb = mb >> 10, nn = mb & 1023;
#pragma unroll
      for (int nt = 0; nt < 4; ++nt) {
        int c = n0 + wc * 16 + nt * 64 + l15;
        int cc = c & 1023;
        int h = cc >> 7, e = cc & 127;
        float bias = bp[cc];
        if (seg == 2) {
          ushort4v pv;
#pragma unroll
          for (int r = 0; r < 4; ++r) pv[r] = f2bf(acc[ai][nt][r] + bias);
          *(ushort4v*)(out2 + ((size_t)(bb * NH + h) * HDIM + e) * BN + nn) = pv;
        } else {
          unsigned short* op = (seg == 0) ? out0 : out1;
#pragma unroll
          for (int r = 0; r < 4; ++r)
            op[(((size_t)bb * NH + h) * BN + (nn + r)) * HDIM + e] =
                f2bf(acc[ai][nt][r] + bias);
        }
      }
    }
  } else {
#pragma unroll
    for (int ai = 0; ai < 8; ++ai) {
      int mb = m0 + wr * 16 + ai * 32 + quad * 4;
#pragma unroll
      for (int nt = 0; nt < 4; ++nt) {
        int c = n0 + wc * 16 + nt * 64 + l15;
        float bias = bias0[c];
#pragma unroll
        for (int r = 0; r < 4; ++r)
          outf[(size_t)(mb + r) * DD + c] = acc[ai][nt][r] + bias;
      }
    }
  }
}

// ---------------------------------------------------------------------------
// K4: flash attention v6 — 2x2 wave split to kill LDS-read redundancy.
// (unchanged this round)
// ---------------------------------------------------------------------------
__global__ __launch_bounds__(256, 2) void flash_attn_kernel(
    const unsigned short* __restrict__ Q, const unsigned short* __restrict__ Kk,
    const unsigned short* __restrict__ Vt, const int* __restrict__ xmask,
    unsigned short* __restrict__ O) {
  __shared__ unsigned short k_s[64 * 128];       // 16 KB, swizzled
  __shared__ unsigned short v_s[2][128 * 64];    // 32 KB, swizzled, dbuf
  __shared__ unsigned short p_s[128 * 72];       // 18 KB, padded (shared P)
  __shared__ float l_s[2][128];                  // 1 KB

  const float CL2E = 0.08838834764831845f * 1.44269504088896f;  // SCALE*log2(e)

  const int tid = threadIdx.x;
  const int w = tid >> 6, lane = tid & 63, quad = lane >> 4, l15 = lane & 15;
  const int wq = w >> 1, wk = w & 1;             // we == wk
  const int lin = blockIdx.x;
  const int bh = lin & 127, qb = lin >> 7;
  const int b = bh >> 3, h = bh & 7;
  const int q0 = qb * 128;
  const unsigned short* qp = Q + ((size_t)bh * BN + q0) * HDIM;
  const unsigned short* kp = Kk + (size_t)bh * BN * HDIM;
  const unsigned short* vp = Vt + (size_t)bh * HDIM * BN;
  const int* xm_b = xmask + b * BN;

  // Q fragments (A-layout) for 64 rows: row = wq*64 + mt*16 + l15
  bf16x8 qf[4][4];
#pragma unroll
  for (int mt = 0; mt < 4; ++mt)
#pragma unroll
    for (int ks = 0; ks < 4; ++ks)
      qf[mt][ks] = *(const bf16x8*)(qp + (wq * 64 + mt * 16 + l15) * HDIM + ks * 32 + quad * 8);

  // row masks packed: bit (mt*4+r) for row wq*64 + mt*16 + quad*4 + r
  int rowm_bits = 0;
#pragma unroll
  for (int mt = 0; mt < 4; ++mt)
#pragma unroll
    for (int r = 0; r < 4; ++r)
      rowm_bits |= (xm_b[q0 + wq * 64 + mt * 16 + quad * 4 + r] ? 1 : 0) << (mt * 4 + r);

  // staging lane decomposition (same swizzles as R5: measured conflict-free)
  const int krow = lane >> 4;
  const int vrow = lane >> 3;
  const int vch = ((lane & 7) - vrow) & 7;

  float l_lane[4][4] = {};
  f32x4 o_acc[4][4] = {};

  // pre-issue tile 0
#pragma unroll
  for (int i = 0; i < 4; ++i) {
    int rmod = i * 4 + krow;
    int g = ((lane & 15) - rmod) & 15;
    async16(kp + (size_t)(w * 16 + rmod) * HDIM + g * 8, k_s + (w * 16 + i * 4) * 128);
    int e = w * 32 + i * 8 + vrow;
    async16(vp + (size_t)e * BN + vch * 8, v_s[0] + (w * 32 + i * 8) * 64);
  }

  for (int it = 0; it < 16; ++it) {
    const int kb = it * 64;
    int cm0 = xm_b[kb + wk * 32 + l15];
    int cm1 = xm_b[kb + wk * 32 + 16 + l15];
    __syncthreads();  // sync_a: K/V tiles arrived; prev p_s reads done

    // S slice = Q[wq-half] K^T[wk-half]  (64q x 32k)
    f32x4 s[4][2] = {};
#pragma unroll
    for (int ks = 0; ks < 4; ++ks) {
      const int sl = ((ks * 4 + quad + l15) & 15) * 8;
      bf16x8 b0 = *(const bf16x8*)(k_s + (wk * 32 + l15) * 128 + sl);
      bf16x8 b1 = *(const bf16x8*)(k_s + (wk * 32 + 16 + l15) * 128 + sl);
#pragma unroll
      for (int mt = 0; mt < 4; ++mt) {
        s[mt][0] = mfma16(qf[mt][ks], b0, s[mt][0]);
        s[mt][1] = mfma16(qf[mt][ks], b1, s[mt][1]);
      }
    }

    // fixed-max softmax -> shared p_s, accumulate partial l per lane
#pragma unroll
    for (int mt = 0; mt < 4; ++mt)
#pragma unroll
      for (int nt = 0; nt < 2; ++nt) {
        int cmv = nt ? cm1 : cm0;
#pragma unroll
        for (int r = 0; r < 4; ++r) {
          float xs = s[mt][nt][r] * CL2E;
          float t = cmv ? xs : -60.0f;
          int rb = (rowm_bits >> (mt * 4 + r)) & 1;
          float e2 = rb ? t : 0.0f;
          float p = __builtin_amdgcn_exp2f(e2);
          l_lane[mt][r] += p;
          p_s[(wq * 64 + mt * 16 + quad * 4 + r) * 72 + wk * 32 + nt * 16 + l15] = f2bf(p);
        }
      }

    __syncthreads();  // sync_b: p_s complete; all k_s reads done

    // prefetch next K/V (wrapped on last iter; harmless re-read)
    {
      const int kn = (kb + 64) & (BN - 1);
      unsigned short* vb_next = v_s[(it + 1) & 1];
#pragma unroll
      for (int i = 0; i < 4; ++i) {
        int rmod = i * 4 + krow;
        int g = ((lane & 15) - rmod) & 15;
        async16(kp + (size_t)(kn + w * 16 + rmod) * HDIM + g * 8,
                k_s + (w * 16 + i * 4) * 128);
        int e = w * 32 + i * 8 + vrow;
        async16(vp + (size_t)e * BN + kn + vch * 8, vb_next + (w * 32 + i * 8) * 64);
      }
    }

    // O slice += P[wq-half][64k] V[64k][we-half]  (64q x 64e)
    const unsigned short* vb = v_s[it & 1];
#pragma unroll
    for (int ks2 = 0; ks2 < 2; ++ks2) {
      const int sl = ((ks2 * 4 + quad + l15) & 7) * 8;
      bf16x8 pa[4];
#pragma unroll
      for (int mt = 0; mt < 4; ++mt)
        pa[mt] = *(const bf16x8*)(p_s + (wq * 64 + mt * 16 + l15) * 72 + ks2 * 32 + quad * 8);
#pragma unroll
      for (int et = 0; et < 4; ++et) {
        bf16x8 bv = *(const bf16x8*)(vb + (wk * 64 + et * 16 + l15) * 64 + sl);
#pragma unroll
        for (int mt = 0; mt < 4; ++mt)
          o_acc[mt][et] = mfma16(pa[mt], bv, o_acc[mt][et]);
      }
    }
  }

  // merge partial l across the two k-half waves via LDS
#pragma unroll
  for (int mt = 0; mt < 4; ++mt)
#pragma unroll
    for (int r = 0; r < 4; ++r) {
      float l = l_lane[mt][r];
#pragma unroll
      for (int off = 1; off < 16; off <<= 1) l += __shfl_xor(l, off, 64);
      if (l15 == 0) l_s[wk][wq * 64 + mt * 16 + quad * 4 + r] = l;
    }
  __syncthreads();

  // epilogue: O/l, store slice [64q x 64e]
#pragma unroll
  for (int mt = 0; mt < 4; ++mt)
#pragma unroll
    for (int r = 0; r < 4; ++r) {
      int rl = wq * 64 + mt * 16 + quad * 4 + r;
      float inv = 1.0f / (l_s[0][rl] + l_s[1][rl]);
      int row = q0 + rl;
#pragma unroll
      for (int et = 0; et < 4; ++et) {
        int col = h * HDIM + wk * 64 + et * 16 + l15;
        O[((size_t)b * BN + row) * DD + col] = f2bf(o_acc[mt][et][r] * inv);
      }
    }
}

// ---------------------------------------------------------------------------
// Workspace layout (bytes): total ~168 MB
//   x_bf @0 33554432 | wqkvT @33554432 6291456 | wfcT @39845888 2097152
//   q_bf @41943040 | k_bf @75497472 | vT_bf @109051904 | o_bf @142606336 (each 33554432)
// ---------------------------------------------------------------------------
extern "C" void kernel_launch(void* const* d_in, const int* in_sizes, int n_in,
                              void* d_out, int out_size, void* d_ws, size_t ws_size,
                              hipStream_t stream) {
  const float* x = (const float*)d_in[0];
  const int* xmask = (const int*)d_in[1];
  const float* Wq = (const float*)d_in[2];
  const float* bq = (const float*)d_in[3];
  const float* Wk = (const float*)d_in[4];
  const float* bk = (const float*)d_in[5];
  const float* Wv = (const float*)d_in[6];
  const float* bv = (const float*)d_in[7];
  const float* Wfc = (const float*)d_in[8];
  const float* bfc = (const float*)d_in[9];
  float* out = (float*)d_out;

  char* ws = (char*)d_ws;
  unsigned short* x_bf  = (unsigned short*)(ws);
  unsigned short* wqkvT = (unsigned short*)(ws + 33554432);
  unsigned short* wfcT  = (unsigned short*)(ws + 39845888);
  unsigned short* q_bf  = (unsigned short*)(ws + 41943040);
  unsigned short* k_bf  = (unsigned short*)(ws + 75497472);
  unsigned short* vT_bf = (unsigned short*)(ws + 109051904);
  unsigned short* o_bf  = (unsigned short*)(ws + 142606336);

  prep_kernel<<<dim3(20480), dim3(256), 0, stream>>>(x, Wq, Wk, Wv, Wfc, x_bf, wqkvT, wfcT);

  // QKV: M=16384, N=3072 -> 64 x 12 = 768 blocks (exactly 3 waves of 256 CUs)
  gemm256_kernel<0><<<dim3(768), dim3(512), 0, stream>>>(
      x_bf, wqkvT, bq, bk, bv, q_bf, k_bf, vT_bf, nullptr);

  flash_attn_kernel<<<dim3(1024), dim3(256), 0, stream>>>(q_bf, k_bf, vT_bf, xmask, o_bf);

  // FC: M=16384, N=1024 -> 64 x 4 = 256 blocks (exactly 1 per CU)
  gemm256_kernel<1><<<dim3(256), dim3(512), 0, stream>>>(
      o_bf, wfcT, bfc, nullptr, nullptr, nullptr, nullptr, nullptr, out);
}

// Round 4
// 395.018 us; speedup vs baseline: 1.0317x; 1.0148x over previous
//
#include <hip/hip_runtime.h>
#include <hip/hip_bf16.h>
#include <math.h>

// Problem: B=16, N=1024, D=1024, H=8, HD=128
#define BN 1024
#define DD 1024
#define NB 16
#define NH 8
#define HDIM 128

typedef __attribute__((ext_vector_type(8))) short bf16x8;
typedef __attribute__((ext_vector_type(4))) float f32x4;
typedef __attribute__((ext_vector_type(16))) float f32x16;
typedef __attribute__((ext_vector_type(4))) unsigned short ushort4v;

#define DEV __device__ __forceinline__

DEV unsigned short f2bf(float f) {
  unsigned u = __float_as_uint(f);
  u = (u + 0x7fffu + ((u >> 16) & 1u)) >> 16;  // RNE
  return (unsigned short)u;
}

DEV f32x4 mfma16(bf16x8 a, bf16x8 b, f32x4 c) {
  return __builtin_amdgcn_mfma_f32_16x16x32_bf16(a, b, c, 0, 0, 0);
}

DEV f32x16 mfma32(bf16x8 a, bf16x8 b, f32x16 c) {
  return __builtin_amdgcn_mfma_f32_32x32x16_bf16(a, b, c, 0, 0, 0);
}

// async global->LDS, 16B per lane. LDS dest = wave-uniform base + lane*16.
DEV void async16(const unsigned short* g, unsigned short* l) {
  __builtin_amdgcn_global_load_lds(
      (const __attribute__((address_space(1))) unsigned short*)g,
      (__attribute__((address_space(3))) unsigned short*)l, 16, 0, 0);
}

// packed f32->2xbf16 (RNE) — no builtin on gfx950 (m240), inline asm
DEV unsigned cvtpk(float lo, float hi_) {
  unsigned r;
  asm("v_cvt_pk_bf16_f32 %0, %1, %2" : "=v"(r) : "v"(lo), "v"(hi_));
  return r;
}
// v_permlane32_swap: a' = {a.lo-lanes, b.lo-lanes}, b' = {a.hi-lanes, b.hi-lanes}
DEV void swap32(unsigned& a, unsigned& b) {
  asm volatile("v_permlane32_swap_b32 %0, %1" : "+v"(a), "+v"(b));
}
DEV bf16x8 mk8(unsigned a, unsigned b, unsigned c, unsigned d) {
  union { unsigned u[4]; bf16x8 v; } t;
  t.u[0] = a; t.u[1] = b; t.u[2] = c; t.u[3] = d;
  return t.v;
}

// ---------------------------------------------------------------------------
// K0 (fused prep): conv_x | transpose_qkv | transpose_fc, branched on blockIdx
// ---------------------------------------------------------------------------
__global__ __launch_bounds__(256) void prep_kernel(
    const float* __restrict__ x, const float* __restrict__ Wq,
    const float* __restrict__ Wk, const float* __restrict__ Wv,
    const float* __restrict__ Wfc, unsigned short* __restrict__ x_bf,
    unsigned short* __restrict__ wqkvT, unsigned short* __restrict__ wfcT) {
  __shared__ float tile[32][33];
  const int bx = blockIdx.x, tid = threadIdx.x;
  if (bx < 16384) {
    int i = bx * 256 + tid;
    const float4* p = (const float4*)x;
    float4 v = p[i];
    ushort4v o;
    o[0] = f2bf(v.x); o[1] = f2bf(v.y); o[2] = f2bf(v.z); o[3] = f2bf(v.w);
    *(ushort4v*)(x_bf + (size_t)i * 4) = o;
    return;
  }
  const int tx = tid & 31, ty = tid >> 5;
  if (bx < 19456) {
    int idx = bx - 16384;
    int k0 = (idx & 31) * 32, e0 = ((idx >> 5) & 3) * 32, z = idx >> 7;
    int which = z >> 3, h = z & 7;
    const float* in = (which == 0 ? Wq : (which == 1 ? Wk : Wv)) + (size_t)h * DD * HDIM;
#pragma unroll
    for (int i = 0; i < 4; ++i)
      tile[ty + i * 8][tx] = in[(size_t)(k0 + ty + i * 8) * HDIM + e0 + tx];
    __syncthreads();
    int rowbase = which * 1024 + h * 128 + e0;
#pragma unroll
    for (int i = 0; i < 4; ++i)
      wqkvT[(size_t)(rowbase + ty + i * 8) * DD + k0 + tx] = f2bf(tile[tx][ty + i * 8]);
  } else {
    int idx = bx - 19456;
    int d0 = (idx & 31) * 32, c0 = (idx >> 5) * 32;
#pragma unroll
    for (int i = 0; i < 4; ++i)
      tile[ty + i * 8][tx] = Wfc[(size_t)(d0 + ty + i * 8) * DD + c0 + tx];
    __syncthreads();
#pragma unroll
    for (int i = 0; i < 4; ++i)
      wfcT[(size_t)(c0 + ty + i * 8) * DD + d0 + tx] = f2bf(tile[tx][ty + i * 8]);
  }
}

// ---------------------------------------------------------------------------
// GEMM (v1, known-good): C[16384][Nc] = A * Bt^T, bf16 MFMA 16x16x32.
// 128x128 tile, BK=64, 4 waves 2x2, swizzled async16 staging (measured
// 0 bank conflicts). R1-R3 established the 256^2 8-phase ports do not beat
// this structure on this problem (all ~32% MfmaUtil); reverted to best.
// ---------------------------------------------------------------------------
template <int MODE>
__global__ __launch_bounds__(256, 3) void gemm128_kernel(
    const unsigned short* __restrict__ A, const unsigned short* __restrict__ Bt,
    const float* __restrict__ bias0, const float* __restrict__ bias1,
    const float* __restrict__ bias2, unsigned short* __restrict__ out0,
    unsigned short* __restrict__ out1, unsigned short* __restrict__ out2,
    float* __restrict__ outf) {
  __shared__ unsigned short as[128 * 64];
  __shared__ unsigned short bs[128 * 64];
  const int tid = threadIdx.x;
  const int wave = tid >> 6, lane = tid & 63, quad = lane >> 4, l15 = lane & 15;
  const int wr = wave >> 1, wc = wave & 1;
  const int m0 = (blockIdx.x & 127) << 7, n0 = (blockIdx.x >> 7) << 7;
  f32x4 acc[4][4] = {};

  const int srow = wave * 32 + (lane >> 3);
  const int gch = ((lane & 7) - (lane >> 3)) & 7;
  const unsigned short* ag = A + (size_t)(m0 + srow) * 1024 + gch * 8;
  const unsigned short* bg = Bt + (size_t)(n0 + srow) * 1024 + gch * 8;
  unsigned short* as_w = as + wave * 32 * 64;
  unsigned short* bs_w = bs + wave * 32 * 64;

  for (int kb = 0; kb < 1024; kb += 64) {
#pragma unroll
    for (int i = 0; i < 4; ++i) {
      async16(ag + kb + i * 8 * 1024, as_w + i * 512);
      async16(bg + kb + i * 8 * 1024, bs_w + i * 512);
    }
    __syncthreads();
#pragma unroll
    for (int ks = 0; ks < 2; ++ks) {
      const int sl = ((quad + ks * 4 + l15) & 7) * 8;
      bf16x8 af[4], bfr[4];
#pragma unroll
      for (int mt = 0; mt < 4; ++mt)
        af[mt] = *(const bf16x8*)(as + (wr * 64 + mt * 16 + l15) * 64 + sl);
#pragma unroll
      for (int nt = 0; nt < 4; ++nt)
        bfr[nt] = *(const bf16x8*)(bs + (wc * 64 + nt * 16 + l15) * 64 + sl);
#pragma unroll
      for (int mt = 0; mt < 4; ++mt)
#pragma unroll
        for (int nt = 0; nt < 4; ++nt)
          acc[mt][nt] = mfma16(af[mt], bfr[nt], acc[mt][nt]);
    }
    __syncthreads();
  }

  if constexpr (MODE == 0) {
    const int seg = n0 >> 10;  // 0=q 1=k 2=v
#pragma unroll
    for (int mt = 0; mt < 4; ++mt) {
      int mb = m0 + wr * 64 + mt * 16 + quad * 4;
      int bb = mb >> 10, nn = mb & 1023;
#pragma unroll
      for (int nt = 0; nt < 4; ++nt) {
        int c = n0 + wc * 64 + nt * 16 + l15;
        int cc = c & 1023;
        int h = cc >> 7, e = cc & 127;
        if (seg == 2) {
          float bias = bias2[cc];
          ushort4v pv;
#pragma unroll
          for (int r = 0; r < 4; ++r) pv[r] = f2bf(acc[mt][nt][r] + bias);
          *(ushort4v*)(out2 + ((size_t)(bb * NH + h) * HDIM + e) * BN + nn) = pv;
        } else {
          const float* bp = (seg == 0) ? bias0 : bias1;
          unsigned short* op = (seg == 0) ? out0 : out1;
          float bias = bp[cc];
#pragma unroll
          for (int r = 0; r < 4; ++r)
            op[(((size_t)bb * NH + h) * BN + (nn + r)) * HDIM + e] =
                f2bf(acc[mt][nt][r] + bias);
        }
      }
    }
  } else {
#pragma unroll
    for (int mt = 0; mt < 4; ++mt) {
      int mb = m0 + wr * 64 + mt * 16 + quad * 4;
#pragma unroll
      for (int nt = 0; nt < 4; ++nt) {
        int c = n0 + wc * 64 + nt * 16 + l15;
        float bias = bias0[c];
#pragma unroll
        for (int r = 0; r < 4; ++r)
          outf[(size_t)(mb + r) * DD + c] = acc[mt][nt][r] + bias;
      }
    }
  }
}

// ---------------------------------------------------------------------------
// K4: flash attention v7 — swapped QK^T on 32x32x16 + in-register softmax.
//
// Each of 4 waves owns 32 q-rows (q = w*32 + (lane&31)) and processes the
// FULL 64-k KV tile. S^T = mfma32(K_frag, Q_frag): C col = lane&31 = q (lane-
// local row!), C row = (reg&3)+8*(reg>>2)+4*(lane>>5) = k  [HW-verified
// mapping, m74/m101]. Softmax entirely in registers (no p_s round-trip,
// no cross-l15 reduce); P -> PV A-frags via v_cvt_pk_bf16_f32 +
// v_permlane32_swap (T12): per 16-k slot, A-frag words
//   w0' = swap(pk(p0,p1), pk(p4,p5)).a   w2' = .b
//   w1' = swap(pk(p2,p3), pk(p6,p7)).a   w3' = .b
// (index-verified: lane(q,hi) slot ks gets exactly P[q][ks*16+hi*8+j]).
// l: scalar per lane, one shfl_xor(32) at end + LDS broadcast for epilogue.
//
// LDS: k_s 16KB + v_s 32KB dbuf + l_s 0.5KB = 49.5KB -> 3 blocks/CU
// (was 68.6KB/2 blocks). MFMA instr count halved (32x32 rate 2382 vs 2075).
// Staging/DMA/swizzles byte-identical to verified v6.
// ---------------------------------------------------------------------------
__global__ __launch_bounds__(256, 2) void flash_attn_kernel(
    const unsigned short* __restrict__ Q, const unsigned short* __restrict__ Kk,
    const unsigned short* __restrict__ Vt, const int* __restrict__ xmask,
    unsigned short* __restrict__ O) {
  __shared__ unsigned short k_s[64 * 128];     // 16 KB, rot-swizzle mod-16
  __shared__ unsigned short v_s[2][128 * 64];  // 32 KB, rot-swizzle mod-8, dbuf
  __shared__ float l_s[128];

  const float CL2E = 0.08838834764831845f * 1.44269504088896f;  // SCALE*log2(e)

  const int tid = threadIdx.x;
  const int w = tid >> 6, lane = tid & 63;
  const int l31 = lane & 31, hi = lane >> 5;
  const int lin = blockIdx.x;
  const int bh = lin & 127, qb = lin >> 7;
  const int b = bh >> 3, h = bh & 7;
  const int q0 = qb * 128;
  const unsigned short* qp = Q + ((size_t)bh * BN + q0) * HDIM;
  const unsigned short* kp = Kk + (size_t)bh * BN * HDIM;
  const unsigned short* vp = Vt + (size_t)bh * HDIM * BN;
  const int* xm_b = xmask + b * BN;

  // Q frags (B-operand of 32x32x16): col=q=w*32+l31, d = dk*16 + hi*8 + j
  bf16x8 qf[8];
#pragma unroll
  for (int dk = 0; dk < 8; ++dk)
    qf[dk] = *(const bf16x8*)(qp + (size_t)(w * 32 + l31) * HDIM + dk * 16 + hi * 8);

  const int rm = xm_b[q0 + w * 32 + l31];  // row mask for this lane's q

  // staging lane decomposition (identical to v6: measured conflict-free)
  const int krow = lane >> 4;
  const int vrow = lane >> 3;
  const int vch = ((lane & 7) - vrow) & 7;

  float l_lane = 0.0f;
  f32x16 o_acc[4] = {};  // O[q = crow(r,hi)][e = et*32 + l31]

  // pre-issue tile 0 (identical to v6)
#pragma unroll
  for (int i = 0; i < 4; ++i) {
    int rmod = i * 4 + krow;
    int g = ((lane & 15) - rmod) & 15;
    async16(kp + (size_t)(w * 16 + rmod) * HDIM + g * 8, k_s + (w * 16 + i * 4) * 128);
    int e = w * 32 + i * 8 + vrow;
    async16(vp + (size_t)e * BN + vch * 8, v_s[0] + (w * 32 + i * 8) * 64);
  }

  for (int it = 0; it < 16; ++it) {
    const int kb = it * 64;
    // column-mask bits for this tile: bit k = xmask[kb+k]
    const unsigned long long mb = __ballot(xm_b[kb + lane] != 0);
    const unsigned long long mbh = mb >> (4 * hi);

    __syncthreads();  // sync_a: K/V tiles arrived (vmcnt drained by syncthreads)

    // S^T slices: s0 = k rows [0,32), s1 = [32,64), this wave's 32 q cols
    f32x16 s0 = {}, s1 = {};
#pragma unroll
    for (int dk = 0; dk < 8; ++dk) {
      const int cc = (2 * dk + hi + (l31 & 15)) & 15;  // rot-swizzle chunk
      bf16x8 k0 = *(const bf16x8*)(k_s + (size_t)l31 * 128 + cc * 8);
      bf16x8 k1 = *(const bf16x8*)(k_s + (size_t)(32 + l31) * 128 + cc * 8);
      s0 = mfma32(k0, qf[dk], s0);
      s1 = mfma32(k1, qf[dk], s1);
    }

    // in-register softmax (fixed-max): p = exp2(scale*s) with masks
    float p0[16], p1[16];
#pragma unroll
    for (int r = 0; r < 16; ++r) {
      const int sh = (r & 3) + 8 * (r >> 2);  // k = sh + 4*hi (+32 for s1)
      float x0 = s0[r] * CL2E, x1 = s1[r] * CL2E;
      float t0 = ((mbh >> sh) & 1) ? x0 : -60.0f;
      float t1 = ((mbh >> (sh + 32)) & 1) ? x1 : -60.0f;
      float e0 = rm ? t0 : 0.0f;
      float e1 = rm ? t1 : 0.0f;
      p0[r] = __builtin_amdgcn_exp2f(e0);
      p1[r] = __builtin_amdgcn_exp2f(e1);
      l_lane += p0[r] + p1[r];
    }

    // pack P -> PV A-frags (4 slots of 16 k): cvt_pk + permlane32_swap
    bf16x8 pa0, pa1, pa2, pa3;
    {
      unsigned a0 = cvtpk(p0[0], p0[1]), a1 = cvtpk(p0[2], p0[3]);
      unsigned a2 = cvtpk(p0[4], p0[5]), a3 = cvtpk(p0[6], p0[7]);
      unsigned b0 = cvtpk(p0[8], p0[9]), b1 = cvtpk(p0[10], p0[11]);
      unsigned b2 = cvtpk(p0[12], p0[13]), b3 = cvtpk(p0[14], p0[15]);
      swap32(a0, a2); swap32(a1, a3); swap32(b0, b2); swap32(b1, b3);
      pa0 = mk8(a0, a1, a2, a3);
      pa1 = mk8(b0, b1, b2, b3);
      unsigned c0 = cvtpk(p1[0], p1[1]), c1 = cvtpk(p1[2], p1[3]);
      unsigned c2 = cvtpk(p1[4], p1[5]), c3 = cvtpk(p1[6], p1[7]);
      unsigned d0 = cvtpk(p1[8], p1[9]), d1 = cvtpk(p1[10], p1[11]);
      unsigned d2 = cvtpk(p1[12], p1[13]), d3 = cvtpk(p1[14], p1[15]);
      swap32(c0, c2); swap32(c1, c3); swap32(d0, d2); swap32(d1, d3);
      pa2 = mk8(c0, c1, c2, c3);
      pa3 = mk8(d0, d1, d2, d3);
    }

    __syncthreads();  // sync_b: all k_s reads done; prev v_s buffer free

    // prefetch next K/V (wrapped on last iter; harmless re-read)
    {
      const int kn = (kb + 64) & (BN - 1);
      unsigned short* vb_next = v_s[(it + 1) & 1];
#pragma unroll
      for (int i = 0; i < 4; ++i) {
        int rmod = i * 4 + krow;
        int g = ((lane & 15) - rmod) & 15;
        async16(kp + (size_t)(kn + w * 16 + rmod) * HDIM + g * 8,
                k_s + (w * 16 + i * 4) * 128);
        int e = w * 32 + i * 8 + vrow;
        async16(vp + (size_t)e * BN + kn + vch * 8, vb_next + (w * 32 + i * 8) * 64);
      }
    }

    // PV: O[32q x 128e] += P[32q x 64k] V[64k x 128e]
    const unsigned short* vb = v_s[it & 1];
    __builtin_amdgcn_s_setprio(1);
#pragma unroll
    for (int et = 0; et < 4; ++et) {
      const int row = et * 32 + l31;
      const int cb = (hi + (row & 7)) & 7;
      // slot ks: V B-frag = vT rows (e), k-chunk 2ks+hi, rot-swizzled
      bf16x8 v0 = *(const bf16x8*)(vb + (size_t)row * 64 + ((cb + 0) & 7) * 8);
      bf16x8 v1 = *(const bf16x8*)(vb + (size_t)row * 64 + ((cb + 2) & 7) * 8);
      bf16x8 v2 = *(const bf16x8*)(vb + (size_t)row * 64 + ((cb + 4) & 7) * 8);
      bf16x8 v3 = *(const bf16x8*)(vb + (size_t)row * 64 + ((cb + 6) & 7) * 8);
      o_acc[et] = mfma32(pa0, v0, o_acc[et]);
      o_acc[et] = mfma32(pa1, v1, o_acc[et]);
      o_acc[et] = mfma32(pa2, v2, o_acc[et]);
      o_acc[et] = mfma32(pa3, v3, o_acc[et]);
    }
    __builtin_amdgcn_s_setprio(0);
  }

  // final l per q: lane + lane^32, broadcast via LDS for epilogue
  l_lane += __shfl_xor(l_lane, 32, 64);
  if (hi == 0) l_s[w * 32 + l31] = l_lane;
  __syncthreads();

  // epilogue: O/l, store. lane holds q = crow(r,hi), e = et*32 + l31
#pragma unroll
  for (int r = 0; r < 16; ++r) {
    const int ql = (r & 3) + 8 * (r >> 2) + 4 * hi;
    const float inv = 1.0f / l_s[w * 32 + ql];
    const int row = q0 + w * 32 + ql;
#pragma unroll
    for (int et = 0; et < 4; ++et) {
      const int col = h * HDIM + et * 32 + l31;
      O[((size_t)b * BN + row) * DD + col] = f2bf(o_acc[et][r] * inv);
    }
  }
}

// ---------------------------------------------------------------------------
// Workspace layout (bytes): total ~168 MB
//   x_bf @0 33554432 | wqkvT @33554432 6291456 | wfcT @39845888 2097152
//   q_bf @41943040 | k_bf @75497472 | vT_bf @109051904 | o_bf @142606336 (each 33554432)
// ---------------------------------------------------------------------------
extern "C" void kernel_launch(void* const* d_in, const int* in_sizes, int n_in,
                              void* d_out, int out_size, void* d_ws, size_t ws_size,
                              hipStream_t stream) {
  const float* x = (const float*)d_in[0];
  const int* xmask = (const int*)d_in[1];
  const float* Wq = (const float*)d_in[2];
  const float* bq = (const float*)d_in[3];
  const float* Wk = (const float*)d_in[4];
  const float* bk = (const float*)d_in[5];
  const float* Wv = (const float*)d_in[6];
  const float* bv = (const float*)d_in[7];
  const float* Wfc = (const float*)d_in[8];
  const float* bfc = (const float*)d_in[9];
  float* out = (float*)d_out;

  char* ws = (char*)d_ws;
  unsigned short* x_bf  = (unsigned short*)(ws);
  unsigned short* wqkvT = (unsigned short*)(ws + 33554432);
  unsigned short* wfcT  = (unsigned short*)(ws + 39845888);
  unsigned short* q_bf  = (unsigned short*)(ws + 41943040);
  unsigned short* k_bf  = (unsigned short*)(ws + 75497472);
  unsigned short* vT_bf = (unsigned short*)(ws + 109051904);
  unsigned short* o_bf  = (unsigned short*)(ws + 142606336);

  prep_kernel<<<dim3(20480), dim3(256), 0, stream>>>(x, Wq, Wk, Wv, Wfc, x_bf, wqkvT, wfcT);

  gemm128_kernel<0><<<dim3(3072), dim3(256), 0, stream>>>(
      x_bf, wqkvT, bq, bk, bv, q_bf, k_bf, vT_bf, nullptr);

  flash_attn_kernel<<<dim3(1024), dim3(256), 0, stream>>>(q_bf, k_bf, vT_bf, xmask, o_bf);

  gemm128_kernel<1><<<dim3(1024), dim3(256), 0, stream>>>(
      o_bf, wfcT, bfc, nullptr, nullptr, nullptr, nullptr, nullptr, out);
}

// Round 5
// 394.227 us; speedup vs baseline: 1.0338x; 1.0020x over previous
//
#include <hip/hip_runtime.h>
#include <hip/hip_bf16.h>
#include <math.h>

// Problem: B=16, N=1024, D=1024, H=8, HD=128
#define BN 1024
#define DD 1024
#define NB 16
#define NH 8
#define HDIM 128

typedef __attribute__((ext_vector_type(8))) short bf16x8;
typedef __attribute__((ext_vector_type(4))) float f32x4;
typedef __attribute__((ext_vector_type(16))) float f32x16;
typedef __attribute__((ext_vector_type(4))) unsigned short ushort4v;

#define DEV __device__ __forceinline__

DEV unsigned short f2bf(float f) {
  unsigned u = __float_as_uint(f);
  u = (u + 0x7fffu + ((u >> 16) & 1u)) >> 16;  // RNE
  return (unsigned short)u;
}

DEV f32x4 mfma16(bf16x8 a, bf16x8 b, f32x4 c) {
  return __builtin_amdgcn_mfma_f32_16x16x32_bf16(a, b, c, 0, 0, 0);
}

DEV f32x16 mfma32(bf16x8 a, bf16x8 b, f32x16 c) {
  return __builtin_amdgcn_mfma_f32_32x32x16_bf16(a, b, c, 0, 0, 0);
}

// async global->LDS, 16B per lane. LDS dest = wave-uniform base + lane*16.
DEV void async16(const unsigned short* g, unsigned short* l) {
  __builtin_amdgcn_global_load_lds(
      (const __attribute__((address_space(1))) unsigned short*)g,
      (__attribute__((address_space(3))) unsigned short*)l, 16, 0, 0);
}

// packed f32->2xbf16 (RNE) — no builtin on gfx950 (m240), inline asm
DEV unsigned cvtpk(float lo, float hi_) {
  unsigned r;
  asm("v_cvt_pk_bf16_f32 %0, %1, %2" : "=v"(r) : "v"(lo), "v"(hi_));
  return r;
}
// v_permlane32_swap: a' = {a.lo-lanes, b.lo-lanes}, b' = {a.hi-lanes, b.hi-lanes}
DEV void swap32(unsigned& a, unsigned& b) {
  asm volatile("v_permlane32_swap_b32 %0, %1" : "+v"(a), "+v"(b));
}
DEV bf16x8 mk8(unsigned a, unsigned b, unsigned c, unsigned d) {
  union { unsigned u[4]; bf16x8 v; } t;
  t.u[0] = a; t.u[1] = b; t.u[2] = c; t.u[3] = d;
  return t.v;
}

// ---------------------------------------------------------------------------
// K0 (fused prep): conv_x | transpose_qkv | transpose_fc, branched on blockIdx
// ---------------------------------------------------------------------------
__global__ __launch_bounds__(256) void prep_kernel(
    const float* __restrict__ x, const float* __restrict__ Wq,
    const float* __restrict__ Wk, const float* __restrict__ Wv,
    const float* __restrict__ Wfc, unsigned short* __restrict__ x_bf,
    unsigned short* __restrict__ wqkvT, unsigned short* __restrict__ wfcT) {
  __shared__ float tile[32][33];
  const int bx = blockIdx.x, tid = threadIdx.x;
  if (bx < 16384) {
    int i = bx * 256 + tid;
    const float4* p = (const float4*)x;
    float4 v = p[i];
    ushort4v o;
    o[0] = f2bf(v.x); o[1] = f2bf(v.y); o[2] = f2bf(v.z); o[3] = f2bf(v.w);
    *(ushort4v*)(x_bf + (size_t)i * 4) = o;
    return;
  }
  const int tx = tid & 31, ty = tid >> 5;
  if (bx < 19456) {
    int idx = bx - 16384;
    int k0 = (idx & 31) * 32, e0 = ((idx >> 5) & 3) * 32, z = idx >> 7;
    int which = z >> 3, h = z & 7;
    const float* in = (which == 0 ? Wq : (which == 1 ? Wk : Wv)) + (size_t)h * DD * HDIM;
#pragma unroll
    for (int i = 0; i < 4; ++i)
      tile[ty + i * 8][tx] = in[(size_t)(k0 + ty + i * 8) * HDIM + e0 + tx];
    __syncthreads();
    int rowbase = which * 1024 + h * 128 + e0;
#pragma unroll
    for (int i = 0; i < 4; ++i)
      wqkvT[(size_t)(rowbase + ty + i * 8) * DD + k0 + tx] = f2bf(tile[tx][ty + i * 8]);
  } else {
    int idx = bx - 19456;
    int d0 = (idx & 31) * 32, c0 = (idx >> 5) * 32;
#pragma unroll
    for (int i = 0; i < 4; ++i)
      tile[ty + i * 8][tx] = Wfc[(size_t)(d0 + ty + i * 8) * DD + c0 + tx];
    __syncthreads();
#pragma unroll
    for (int i = 0; i < 4; ++i)
      wfcT[(size_t)(c0 + ty + i * 8) * DD + d0 + tx] = f2bf(tile[tx][ty + i * 8]);
  }
}

// ---------------------------------------------------------------------------
// GEMM (v1, known-good): C[16384][Nc] = A * Bt^T, bf16 MFMA 16x16x32.
// 128x128 tile, BK=64, 4 waves 2x2, swizzled async16 staging (measured
// 0 bank conflicts). R1-R3 established the 256^2 8-phase ports do not beat
// this structure on this problem (all ~32% MfmaUtil); reverted to best.
// ---------------------------------------------------------------------------
template <int MODE>
__global__ __launch_bounds__(256, 3) void gemm128_kernel(
    const unsigned short* __restrict__ A, const unsigned short* __restrict__ Bt,
    const float* __restrict__ bias0, const float* __restrict__ bias1,
    const float* __restrict__ bias2, unsigned short* __restrict__ out0,
    unsigned short* __restrict__ out1, unsigned short* __restrict__ out2,
    float* __restrict__ outf) {
  __shared__ unsigned short as[128 * 64];
  __shared__ unsigned short bs[128 * 64];
  const int tid = threadIdx.x;
  const int wave = tid >> 6, lane = tid & 63, quad = lane >> 4, l15 = lane & 15;
  const int wr = wave >> 1, wc = wave & 1;
  const int m0 = (blockIdx.x & 127) << 7, n0 = (blockIdx.x >> 7) << 7;
  f32x4 acc[4][4] = {};

  const int srow = wave * 32 + (lane >> 3);
  const int gch = ((lane & 7) - (lane >> 3)) & 7;
  const unsigned short* ag = A + (size_t)(m0 + srow) * 1024 + gch * 8;
  const unsigned short* bg = Bt + (size_t)(n0 + srow) * 1024 + gch * 8;
  unsigned short* as_w = as + wave * 32 * 64;
  unsigned short* bs_w = bs + wave * 32 * 64;

  for (int kb = 0; kb < 1024; kb += 64) {
#pragma unroll
    for (int i = 0; i < 4; ++i) {
      async16(ag + kb + i * 8 * 1024, as_w + i * 512);
      async16(bg + kb + i * 8 * 1024, bs_w + i * 512);
    }
    __syncthreads();
#pragma unroll
    for (int ks = 0; ks < 2; ++ks) {
      const int sl = ((quad + ks * 4 + l15) & 7) * 8;
      bf16x8 af[4], bfr[4];
#pragma unroll
      for (int mt = 0; mt < 4; ++mt)
        af[mt] = *(const bf16x8*)(as + (wr * 64 + mt * 16 + l15) * 64 + sl);
#pragma unroll
      for (int nt = 0; nt < 4; ++nt)
        bfr[nt] = *(const bf16x8*)(bs + (wc * 64 + nt * 16 + l15) * 64 + sl);
#pragma unroll
      for (int mt = 0; mt < 4; ++mt)
#pragma unroll
        for (int nt = 0; nt < 4; ++nt)
          acc[mt][nt] = mfma16(af[mt], bfr[nt], acc[mt][nt]);
    }
    __syncthreads();
  }

  if constexpr (MODE == 0) {
    const int seg = n0 >> 10;  // 0=q 1=k 2=v
#pragma unroll
    for (int mt = 0; mt < 4; ++mt) {
      int mb = m0 + wr * 64 + mt * 16 + quad * 4;
      int bb = mb >> 10, nn = mb & 1023;
#pragma unroll
      for (int nt = 0; nt < 4; ++nt) {
        int c = n0 + wc * 64 + nt * 16 + l15;
        int cc = c & 1023;
        int h = cc >> 7, e = cc & 127;
        if (seg == 2) {
          float bias = bias2[cc];
          ushort4v pv;
#pragma unroll
          for (int r = 0; r < 4; ++r) pv[r] = f2bf(acc[mt][nt][r] + bias);
          *(ushort4v*)(out2 + ((size_t)(bb * NH + h) * HDIM + e) * BN + nn) = pv;
        } else {
          const float* bp = (seg == 0) ? bias0 : bias1;
          unsigned short* op = (seg == 0) ? out0 : out1;
          float bias = bp[cc];
#pragma unroll
          for (int r = 0; r < 4; ++r)
            op[(((size_t)bb * NH + h) * BN + (nn + r)) * HDIM + e] =
                f2bf(acc[mt][nt][r] + bias);
        }
      }
    }
  } else {
#pragma unroll
    for (int mt = 0; mt < 4; ++mt) {
      int mb = m0 + wr * 64 + mt * 16 + quad * 4;
#pragma unroll
      for (int nt = 0; nt < 4; ++nt) {
        int c = n0 + wc * 64 + nt * 16 + l15;
        float bias = bias0[c];
#pragma unroll
        for (int r = 0; r < 4; ++r)
          outf[(size_t)(mb + r) * DD + c] = acc[mt][nt][r] + bias;
      }
    }
  }
}

// ---------------------------------------------------------------------------
// K4: flash attention v8 — v7 + K double-buffer -> ONE barrier per iter +
// softmax/PV interleave.
//
// v7 post-mortem: halving MFMA count + in-reg softmax gained only ~8us ->
// attn is serialization-bound, not throughput-bound. v7's chain per iter:
// sync(drain) -> QK -> FULL softmax -> sync(drain) -> DMA issue -> PV.
// Two vmcnt drains/iter; softmax barrier-fenced from PV (no overlap);
// K-prefetch window only ~PV (~500cy).
//
// v8: K and V both double-buffered (LDS 64.5KB, still 2 blocks/CU since
// VGPR ~185 caps at 2 waves/SIMD anyway). Per iter: ONE __syncthreads at
// top (guarantees: tile-t DMA complete CU-wide [own-wave vmcnt drain +
// barrier]; buffer (t+1)&1's last readers [iter t-1] done). Then issue
// DMA(t+1) immediately (full-iteration completion window), then
// QK -> exp(half0) -> pack pa0/pa1 -> PV slots 0,1
//    -> exp(half1) -> pack pa2/pa3 -> PV slots 2,3
// with no intervening barrier: softmax VALU of one half overlaps PV MFMA
// of the other. All index math byte-identical to verified v7.
// ---------------------------------------------------------------------------
__global__ __launch_bounds__(256, 2) void flash_attn_kernel(
    const unsigned short* __restrict__ Q, const unsigned short* __restrict__ Kk,
    const unsigned short* __restrict__ Vt, const int* __restrict__ xmask,
    unsigned short* __restrict__ O) {
  __shared__ unsigned short k_s[2][64 * 128];  // 2x16 KB, rot-swizzle mod-16
  __shared__ unsigned short v_s[2][128 * 64];  // 2x16 KB, rot-swizzle mod-8
  __shared__ float l_s[128];

  const float CL2E = 0.08838834764831845f * 1.44269504088896f;  // SCALE*log2(e)

  const int tid = threadIdx.x;
  const int w = tid >> 6, lane = tid & 63;
  const int l31 = lane & 31, hi = lane >> 5;
  const int lin = blockIdx.x;
  const int bh = lin & 127, qb = lin >> 7;
  const int b = bh >> 3, h = bh & 7;
  const int q0 = qb * 128;
  const unsigned short* qp = Q + ((size_t)bh * BN + q0) * HDIM;
  const unsigned short* kp = Kk + (size_t)bh * BN * HDIM;
  const unsigned short* vp = Vt + (size_t)bh * HDIM * BN;
  const int* xm_b = xmask + b * BN;

  // Q frags (B-operand of 32x32x16): col=q=w*32+l31, d = dk*16 + hi*8 + j
  bf16x8 qf[8];
#pragma unroll
  for (int dk = 0; dk < 8; ++dk)
    qf[dk] = *(const bf16x8*)(qp + (size_t)(w * 32 + l31) * HDIM + dk * 16 + hi * 8);

  const int rm = xm_b[q0 + w * 32 + l31];  // row mask for this lane's q

  // staging lane decomposition (identical to v6/v7: measured conflict-free)
  const int krow = lane >> 4;
  const int vrow = lane >> 3;
  const int vch = ((lane & 7) - vrow) & 7;

  float l_lane = 0.0f;
  f32x16 o_acc[4] = {};  // O[q = crow(r,hi)][e = et*32 + l31]

  // pre-issue tile 0 into buffer 0
#pragma unroll
  for (int i = 0; i < 4; ++i) {
    int rmod = i * 4 + krow;
    int g = ((lane & 15) - rmod) & 15;
    async16(kp + (size_t)(w * 16 + rmod) * HDIM + g * 8, k_s[0] + (w * 16 + i * 4) * 128);
    int e = w * 32 + i * 8 + vrow;
    async16(vp + (size_t)e * BN + vch * 8, v_s[0] + (w * 32 + i * 8) * 64);
  }

  for (int it = 0; it < 16; ++it) {
    const int kb = it * 64;
    const int cur = it & 1, nxt = cur ^ 1;
    // column-mask bits for this tile: bit k = xmask[kb+k]
    const unsigned long long mb = __ballot(xm_b[kb + lane] != 0);
    const unsigned long long mbh = mb >> (4 * hi);

    __syncthreads();  // tile-t DMA complete CU-wide; buffers[nxt] readers done

    // issue DMA(t+1) into the other buffers (wrapped on last iter; harmless)
    {
      const int kn = (kb + 64) & (BN - 1);
      unsigned short* kbn = k_s[nxt];
      unsigned short* vbn = v_s[nxt];
#pragma unroll
      for (int i = 0; i < 4; ++i) {
        int rmod = i * 4 + krow;
        int g = ((lane & 15) - rmod) & 15;
        async16(kp + (size_t)(kn + w * 16 + rmod) * HDIM + g * 8,
                kbn + (w * 16 + i * 4) * 128);
        int e = w * 32 + i * 8 + vrow;
        async16(vp + (size_t)e * BN + kn + vch * 8, vbn + (w * 32 + i * 8) * 64);
      }
    }

    // S^T slices: s0 = k rows [0,32), s1 = [32,64), this wave's 32 q cols
    const unsigned short* kbc = k_s[cur];
    f32x16 s0 = {}, s1 = {};
#pragma unroll
    for (int dk = 0; dk < 8; ++dk) {
      const int cc = (2 * dk + hi + (l31 & 15)) & 15;  // rot-swizzle chunk
      bf16x8 k0 = *(const bf16x8*)(kbc + (size_t)l31 * 128 + cc * 8);
      bf16x8 k1 = *(const bf16x8*)(kbc + (size_t)(32 + l31) * 128 + cc * 8);
      s0 = mfma32(k0, qf[dk], s0);
      s1 = mfma32(k1, qf[dk], s1);
    }

    const unsigned short* vb = v_s[cur];

    // ---- half 0: exp(s0) -> pack pa0,pa1 -> PV slots 0,1 (k 0..31)
    {
      float p0[16];
#pragma unroll
      for (int r = 0; r < 16; ++r) {
        const int sh = (r & 3) + 8 * (r >> 2);  // k = sh + 4*hi
        float x0 = s0[r] * CL2E;
        float t0 = ((mbh >> sh) & 1) ? x0 : -60.0f;
        float e0 = rm ? t0 : 0.0f;
        p0[r] = __builtin_amdgcn_exp2f(e0);
        l_lane += p0[r];
      }
      unsigned a0 = cvtpk(p0[0], p0[1]), a1 = cvtpk(p0[2], p0[3]);
      unsigned a2 = cvtpk(p0[4], p0[5]), a3 = cvtpk(p0[6], p0[7]);
      unsigned b0 = cvtpk(p0[8], p0[9]), b1 = cvtpk(p0[10], p0[11]);
      unsigned b2 = cvtpk(p0[12], p0[13]), b3 = cvtpk(p0[14], p0[15]);
      swap32(a0, a2); swap32(a1, a3); swap32(b0, b2); swap32(b1, b3);
      bf16x8 pa0 = mk8(a0, a1, a2, a3);
      bf16x8 pa1 = mk8(b0, b1, b2, b3);
      __builtin_amdgcn_s_setprio(1);
#pragma unroll
      for (int et = 0; et < 4; ++et) {
        const int row = et * 32 + l31;
        const int cb = (hi + (row & 7)) & 7;
        bf16x8 v0 = *(const bf16x8*)(vb + (size_t)row * 64 + ((cb + 0) & 7) * 8);
        bf16x8 v1 = *(const bf16x8*)(vb + (size_t)row * 64 + ((cb + 2) & 7) * 8);
        o_acc[et] = mfma32(pa0, v0, o_acc[et]);
        o_acc[et] = mfma32(pa1, v1, o_acc[et]);
      }
      __builtin_amdgcn_s_setprio(0);
    }

    // ---- half 1: exp(s1) -> pack pa2,pa3 -> PV slots 2,3 (k 32..63)
    {
      float p1[16];
#pragma unroll
      for (int r = 0; r < 16; ++r) {
        const int sh = (r & 3) + 8 * (r >> 2);
        float x1 = s1[r] * CL2E;
        float t1 = ((mbh >> (sh + 32)) & 1) ? x1 : -60.0f;
        float e1 = rm ? t1 : 0.0f;
        p1[r] = __builtin_amdgcn_exp2f(e1);
        l_lane += p1[r];
      }
      unsigned c0 = cvtpk(p1[0], p1[1]), c1 = cvtpk(p1[2], p1[3]);
      unsigned c2 = cvtpk(p1[4], p1[5]), c3 = cvtpk(p1[6], p1[7]);
      unsigned d0 = cvtpk(p1[8], p1[9]), d1 = cvtpk(p1[10], p1[11]);
      unsigned d2 = cvtpk(p1[12], p1[13]), d3 = cvtpk(p1[14], p1[15]);
      swap32(c0, c2); swap32(c1, c3); swap32(d0, d2); swap32(d1, d3);
      bf16x8 pa2 = mk8(c0, c1, c2, c3);
      bf16x8 pa3 = mk8(d0, d1, d2, d3);
      __builtin_amdgcn_s_setprio(1);
#pragma unroll
      for (int et = 0; et < 4; ++et) {
        const int row = et * 32 + l31;
        const int cb = (hi + (row & 7)) & 7;
        bf16x8 v2 = *(const bf16x8*)(vb + (size_t)row * 64 + ((cb + 4) & 7) * 8);
        bf16x8 v3 = *(const bf16x8*)(vb + (size_t)row * 64 + ((cb + 6) & 7) * 8);
        o_acc[et] = mfma32(pa2, v2, o_acc[et]);
        o_acc[et] = mfma32(pa3, v3, o_acc[et]);
      }
      __builtin_amdgcn_s_setprio(0);
    }
  }

  // final l per q: lane + lane^32, broadcast via LDS for epilogue
  l_lane += __shfl_xor(l_lane, 32, 64);
  if (hi == 0) l_s[w * 32 + l31] = l_lane;
  __syncthreads();

  // epilogue: O/l, store. lane holds q = crow(r,hi), e = et*32 + l31
#pragma unroll
  for (int r = 0; r < 16; ++r) {
    const int ql = (r & 3) + 8 * (r >> 2) + 4 * hi;
    const float inv = 1.0f / l_s[w * 32 + ql];
    const int row = q0 + w * 32 + ql;
#pragma unroll
    for (int et = 0; et < 4; ++et) {
      const int col = h * HDIM + et * 32 + l31;
      O[((size_t)b * BN + row) * DD + col] = f2bf(o_acc[et][r] * inv);
    }
  }
}

// ---------------------------------------------------------------------------
// Workspace layout (bytes): total ~168 MB
//   x_bf @0 33554432 | wqkvT @33554432 6291456 | wfcT @39845888 2097152
//   q_bf @41943040 | k_bf @75497472 | vT_bf @109051904 | o_bf @142606336 (each 33554432)
// ---------------------------------------------------------------------------
extern "C" void kernel_launch(void* const* d_in, const int* in_sizes, int n_in,
                              void* d_out, int out_size, void* d_ws, size_t ws_size,
                              hipStream_t stream) {
  const float* x = (const float*)d_in[0];
  const int* xmask = (const int*)d_in[1];
  const float* Wq = (const float*)d_in[2];
  const float* bq = (const float*)d_in[3];
  const float* Wk = (const float*)d_in[4];
  const float* bk = (const float*)d_in[5];
  const float* Wv = (const float*)d_in[6];
  const float* bv = (const float*)d_in[7];
  const float* Wfc = (const float*)d_in[8];
  const float* bfc = (const float*)d_in[9];
  float* out = (float*)d_out;

  char* ws = (char*)d_ws;
  unsigned short* x_bf  = (unsigned short*)(ws);
  unsigned short* wqkvT = (unsigned short*)(ws + 33554432);
  unsigned short* wfcT  = (unsigned short*)(ws + 39845888);
  unsigned short* q_bf  = (unsigned short*)(ws + 41943040);
  unsigned short* k_bf  = (unsigned short*)(ws + 75497472);
  unsigned short* vT_bf = (unsigned short*)(ws + 109051904);
  unsigned short* o_bf  = (unsigned short*)(ws + 142606336);

  prep_kernel<<<dim3(20480), dim3(256), 0, stream>>>(x, Wq, Wk, Wv, Wfc, x_bf, wqkvT, wfcT);

  gemm128_kernel<0><<<dim3(3072), dim3(256), 0, stream>>>(
      x_bf, wqkvT, bq, bk, bv, q_bf, k_bf, vT_bf, nullptr);

  flash_attn_kernel<<<dim3(1024), dim3(256), 0, stream>>>(q_bf, k_bf, vT_bf, xmask, o_bf);

  gemm128_kernel<1><<<dim3(1024), dim3(256), 0, stream>>>(
      o_bf, wfcT, bfc, nullptr, nullptr, nullptr, nullptr, nullptr, out);
}